// Round 1
// 134.529 us; speedup vs baseline: 1.0226x; 1.0226x over previous
//
#include <hip/hip_runtime.h>
#include <math.h>

// TWO RAYS PER THREAD, thread-per-ray semantics otherwise (R4 numerics exactly).
// R7 forensics: busy cycles are invariant (~37.5 us); only stall-hiding matters.
// Grid caps waves at rays/64; tpr>=4 spills (R5/R6). So: halve waves, double ILP.
// R8 (this round): occupancy is structurally 1 wave/SIMD (1024 waves on 1024
// SIMDs) yet the compiler allocated to a 4-wave heuristic (132 VGPR) and
// `unroll 1` forbade cross-iteration overlap -> the 8-10 independent
// trans chains per iteration were serialized (~635 cy/iter vs ~300 busy).
// Fix: __launch_bounds__(64,1) frees the allocator to 512 VGPRs (LDS already
// pins 4 blocks/CU; nothing to lose), unroll 2/4 on the serial machines gives
// the in-order issue window multiple iterations of independent sigmoid chains,
// and __builtin_amdgcn_exp2f guarantees a bare v_exp_f32.
// Phase 2/3 fully branchless: conditional LDS store -> unconditional store to pad
// row; window refill -> unconditional ds_read. fd columns are per-thread only ->
// zero barriers. LDS 33.3 KB/block, 1024 blocks = 4 blocks/CU = 1 wave/SIMD.

#define NT 64
#define PTS 64
#define NRAYS (2*256*256)
#define NEARV 0.1f
#define STEPV (1.9f/63.0f)
#define FAR63 (0.1f + 63.0f*(1.9f/63.0f))
#define NL2E (-1.4426950408889634f)

__device__ __forceinline__ float sig_pm(float arg) {   // arg is already -x*log2e
    return __builtin_amdgcn_rcpf(1.0f + __builtin_amdgcn_exp2f(arg));
}

__global__ __launch_bounds__(NT, 1) void nerf_main(
    const float* __restrict__ tm, const float* __restrict__ wq,
    float* __restrict__ out, unsigned int* __restrict__ mmx)
{
    __shared__ float fd[2][PTS + 1][NT];   // per-ray fine depths + junk pad row
    const int tid = threadIdx.x;
    int rr[2];
    rr[0] = blockIdx.x * 128 + tid;
    rr[1] = rr[0] + 64;

    float bA[2][4], sA[2][4];              // feat[c]*(-log2e) = bA + d*sA
    int bb_[2], nn_[2];
    #pragma unroll
    for (int q = 0; q < 2; q++) {
        int r = rr[q];
        int b = r >> 16, n = r & 65535;
        bb_[q] = b; nn_[q] = n;
        int i = n >> 8, j = n & 255;
        float cx = (1.0f + (float)j * (-2.0f/255.0f)) * (1.0f/4.2f);
        float cy = (1.0f + (float)i * (-2.0f/255.0f)) * (1.0f/4.2f);
        const float* tmb = tm + b*12;
        float dx = tmb[0]*cx + tmb[1]*cy + tmb[2];
        float dy = tmb[4]*cx + tmb[5]*cy + tmb[6];
        float dz = tmb[8]*cx + tmb[9]*cy + tmb[10];
        float ox = tmb[3], oy = tmb[7], oz = tmb[11];
        #pragma unroll
        for (int c = 0; c < 4; c++) {
            float s  = dx*wq[0*4+c] + dy*wq[1*4+c] + dz*wq[2*4+c];
            float bv = ox*wq[0*4+c] + oy*wq[1*4+c] + oz*wq[2*4+c]
                     + dx*wq[3*4+c] + dy*wq[4*4+c] + dz*wq[5*4+c];
            sA[q][c] = s * NL2E;
            bA[q][c] = bv * NL2E;
        }
    }

    // ---- phase 1: coarse march, 2 rays interleaved ----
    float T[2] = {1.0f, 1.0f}, S[2] = {0.0f, 0.0f};
    float a0[2] = {0.0f, 0.0f}, a1[2] = {0.0f, 0.0f}, a2[2] = {0.0f, 0.0f};
    #pragma unroll 4
    for (int p = 0; p < PTS; p++) {
        float d = fmaf((float)p, STEPV, NEARV);
        #pragma unroll
        for (int q = 0; q < 2; q++) {
            float op = sig_pm(bA[q][0] + d*sA[q][0]);
            float v0 = sig_pm(bA[q][1] + d*sA[q][1]);
            float v1 = sig_pm(bA[q][2] + d*sA[q][2]);
            float v2 = sig_pm(bA[q][3] + d*sA[q][3]);
            float w  = op * T[q];
            a0[q] = fmaf(w, v0, a0[q]);
            a1[q] = fmaf(w, v1, a1[q]);
            a2[q] = fmaf(w, v2, a2[q]);
            S[q] += w + 1e-5f;
            T[q] *= (1.0f - op);
        }
    }
    #pragma unroll
    for (int q = 0; q < 2; q++) {
        out[(bb_[q]*3+0)*65536 + nn_[q]] = a0[q];
        out[(bb_[q]*3+1)*65536 + nn_[q]] = a1[q];
        out[(bb_[q]*3+2)*65536 + nn_[q]] = a2[q];
    }

    // ---- phase 2: branchless sampling machines, interleaved ----
    float Sinv[2], T2[2], c_lo[2], c_hi[2], bin_prev[2];
    int ind[2], kk[2];
    #pragma unroll
    for (int q = 0; q < 2; q++) {
        Sinv[q] = __builtin_amdgcn_rcpf(S[q]);
        float op0 = sig_pm(bA[q][0] + NEARV*sA[q][0]);
        T2[q]   = 1.0f - op0;
        c_lo[q] = 0.0f;
        c_hi[q] = (op0 + 1e-5f) * Sinv[q];   // cdf[0]
        ind[q] = 0; kk[q] = 1;
        bin_prev[q] = NEARV;                 // bin_0 == NEAR always
    }
    #pragma unroll 2
    for (int it = 0; it < 2*PTS; it++) {
        #pragma unroll
        for (int q = 0; q < 2; q++) {
            float u = (float)kk[q] * 0.015625f;          // exact k/64
            bool adv = (ind[q] < PTS) && (c_hi[q] <= u); // searchsorted 'right'
            float dn  = fmaf((float)min(ind[q] + 1, 63), STEPV, NEARV);
            float opn = sig_pm(bA[q][0] + dn*sA[q][0]);
            float wn  = opn * T2[q];
            float d0  = fmaf((float)(ind[q] - 1), STEPV, NEARV);
            float den = c_hi[q] - c_lo[q];
            den = (den < 1e-8f) ? 1.0f : den;            // ref guard
            float t = (u - c_lo[q]) * __builtin_amdgcn_rcpf(den);
            t = fminf(fmaxf(t, 0.0f), 1.0f);
            float bin = fmaf(t, STEPV, d0);
            bin = (ind[q] <= 0)   ? NEARV : bin;
            bin = (ind[q] >= PTS) ? FAR63 : bin;
            float fdep = 0.5f * (bin_prev[q] + bin);
            int widx = adv ? PTS : min(kk[q] - 1, PTS);  // pad row on advance
            fd[q][widx][tid] = fdep;                     // unconditional ds_write
            float nc_hi = c_hi[q] + (wn + 1e-5f) * Sinv[q];
            float nT2   = T2[q] * (1.0f - opn);
            c_lo[q]     = adv ? c_hi[q] : c_lo[q];
            c_hi[q]     = adv ? nc_hi   : c_hi[q];
            T2[q]       = adv ? nT2     : T2[q];
            bin_prev[q] = adv ? bin_prev[q] : bin;
            ind[q] += adv ? 1 : 0;
            kk[q]  += adv ? 0 : 1;
        }
    }

    // ---- phase 3: branchless merge, 2 rays interleaved ----
    float T3[2] = {1.0f, 1.0f}, sw[2] = {0.0f, 0.0f};
    float f0[2] = {0.0f, 0.0f}, f1[2] = {0.0f, 0.0f}, f2[2] = {0.0f, 0.0f};
    float rd[2] = {0.0f, 0.0f};
    int pc[2] = {0, 0}, pf[2] = {0, 0};
    float dc[2] = {NEARV, NEARV};
    float cur[2], nxt[2];
    #pragma unroll
    for (int q = 0; q < 2; q++) { cur[q] = fd[q][0][tid]; nxt[q] = fd[q][1][tid]; }
    #pragma unroll 4
    for (int it = 0; it < 2*PTS; it++) {
        #pragma unroll
        for (int q = 0; q < 2; q++) {
            float dfv = (pf[q] < PTS) ? cur[q] : 3.0e38f;
            bool tc = (pc[q] < PTS) && (dc[q] <= dfv);   // ties -> coarse (stable)
            float d = tc ? dc[q] : dfv;
            pc[q] += tc ? 1 : 0;
            dc[q] = fmaf((float)pc[q], STEPV, NEARV);
            pf[q] += tc ? 0 : 1;
            cur[q] = tc ? cur[q] : nxt[q];
            nxt[q] = fd[q][min(pf[q] + 1, PTS)][tid];    // unconditional ds_read
            float op = sig_pm(bA[q][0] + d*sA[q][0]);
            float v0 = sig_pm(bA[q][1] + d*sA[q][1]);
            float v1 = sig_pm(bA[q][2] + d*sA[q][2]);
            float v2 = sig_pm(bA[q][3] + d*sA[q][3]);
            float w  = op * T3[q];
            f0[q] = fmaf(w, v0, f0[q]);
            f1[q] = fmaf(w, v1, f1[q]);
            f2[q] = fmaf(w, v2, f2[q]);
            sw[q] += w;
            rd[q] = fmaf(w, d, rd[q]);
            T3[q] *= (1.0f - op);
        }
    }

    unsigned kmn = 0xFFFFFFFFu, kmx = 0xFFFFFFFFu;
    #pragma unroll
    for (int q = 0; q < 2; q++) {
        out[393216 + (bb_[q]*3+0)*65536 + nn_[q]] = f0[q];
        out[393216 + (bb_[q]*3+1)*65536 + nn_[q]] = f1[q];
        out[393216 + (bb_[q]*3+2)*65536 + nn_[q]] = f2[q];
        float fop  = fminf(fmaxf(sw[q], 0.0f), 1.0f);
        float rdep = rd[q] + (1.0f - fop) * 2.0f;        // d_all.max() == 2.0 exactly
        out[786432 + rr[q]] = rdep;
        unsigned ub = __float_as_uint(rdep);             // rdep>0: u32 order == float order
        kmn = min(kmn, ub);
        kmx = min(kmx, ~ub);
    }
    #pragma unroll
    for (int m = 32; m >= 1; m >>= 1) {
        unsigned omn = (unsigned)__shfl_xor((int)kmn, m, 64);
        unsigned omx = (unsigned)__shfl_xor((int)kmx, m, 64);
        kmn = (omn < kmn) ? omn : kmn;
        kmx = (omx < kmx) ? omx : kmx;
    }
    if (tid == 0) {
        atomicMin(&mmx[0], kmn);
        atomicMin(&mmx[1], kmx);
    }
}

__global__ __launch_bounds__(256) void nerf_norm(float* __restrict__ out,
                                                 const unsigned int* __restrict__ mmx)
{
    int idx = blockIdx.x * 256 + threadIdx.x;
    float mn = __uint_as_float(mmx[0]);
    float mx = __uint_as_float(~mmx[1]);
    float v = out[786432 + idx];
    out[786432 + idx] = (v - mn) * __builtin_amdgcn_rcpf(mx - mn);
}

extern "C" void kernel_launch(void* const* d_in, const int* in_sizes, int n_in,
                              void* d_out, int out_size, void* d_ws, size_t ws_size,
                              hipStream_t stream) {
    (void)in_sizes; (void)n_in; (void)out_size; (void)ws_size;
    const float* tm = (const float*)d_in[0];
    const float* wq = (const float*)d_in[1];
    float* out = (float*)d_out;
    unsigned int* mmx = (unsigned int*)d_ws;
    hipMemsetAsync(d_ws, 0xFF, 8, stream);     // both min-keys -> UINT_MAX
    nerf_main<<<NRAYS/128, NT, 0, stream>>>(tm, wq, out, mmx);
    nerf_norm<<<NRAYS/256, 256, 0, stream>>>(out, mmx);
}

// Round 2
// 131.619 us; speedup vs baseline: 1.0452x; 1.0221x over previous
//
#include <hip/hip_runtime.h>
#include <math.h>

// TWO RAYS PER THREAD, thread-per-ray semantics otherwise (R4 numerics + ~1e-6
// recurrence rounding). R7 forensics: busy cycles ~invariant; only stall-hiding
// OR WORK REMOVAL matters. R8 (launch_bounds(64,1) + unroll) was falsified:
// VGPR stayed 132, dur 84.7->81.9 -- unrolling a loop-carried state machine
// creates no parallelism.
// R9 (this round): the stall lives on the dependency chains and their dominant
// primitive is v_exp_f32/v_rcp_f32 (1792 sigmoids/thread). The sigmoid args are
// affine in depth and phases 1+2 walk a UNIFORM depth grid monotonically, so
// exp2(bA + d_p*sA) follows a geometric recurrence e_{p+1} = e_p * k with
// k = exp2(sA*STEP): deletes all 768 exp2 (+768 arg fmas) from phases 1+2,
// replaced by one v_mul each, and shortens phase 2's carried c_hi chain from
// fma->exp->add->rcp (~40cy) to mul->add->rcp (~25cy). Phase 3 depths are
// data-dependent (merged order) -> keeps full sigmoids.
// Phase 2/3 fully branchless: conditional LDS store -> unconditional store to pad
// row; window refill -> unconditional ds_read. fd columns are per-thread only ->
// zero barriers. LDS 33.3 KB/block, 1024 blocks = 4 blocks/CU = 1 wave/SIMD.

#define NT 64
#define PTS 64
#define NRAYS (2*256*256)
#define NEARV 0.1f
#define STEPV (1.9f/63.0f)
#define FAR63 (0.1f + 63.0f*(1.9f/63.0f))
#define NL2E (-1.4426950408889634f)

__device__ __forceinline__ float sig_pm(float arg) {   // arg is already -x*log2e
    return __builtin_amdgcn_rcpf(1.0f + __builtin_amdgcn_exp2f(arg));
}
__device__ __forceinline__ float sig_e(float e) {      // e = exp2(-x*log2e)
    return __builtin_amdgcn_rcpf(1.0f + e);
}

__global__ __launch_bounds__(NT, 1) void nerf_main(
    const float* __restrict__ tm, const float* __restrict__ wq,
    float* __restrict__ out, unsigned int* __restrict__ mmx)
{
    __shared__ float fd[2][PTS + 1][NT];   // per-ray fine depths + junk pad row
    const int tid = threadIdx.x;
    int rr[2];
    rr[0] = blockIdx.x * 128 + tid;
    rr[1] = rr[0] + 64;

    float bA[2][4], sA[2][4];              // feat[c]*(-log2e) = bA + d*sA
    int bb_[2], nn_[2];
    #pragma unroll
    for (int q = 0; q < 2; q++) {
        int r = rr[q];
        int b = r >> 16, n = r & 65535;
        bb_[q] = b; nn_[q] = n;
        int i = n >> 8, j = n & 255;
        float cx = (1.0f + (float)j * (-2.0f/255.0f)) * (1.0f/4.2f);
        float cy = (1.0f + (float)i * (-2.0f/255.0f)) * (1.0f/4.2f);
        const float* tmb = tm + b*12;
        float dx = tmb[0]*cx + tmb[1]*cy + tmb[2];
        float dy = tmb[4]*cx + tmb[5]*cy + tmb[6];
        float dz = tmb[8]*cx + tmb[9]*cy + tmb[10];
        float ox = tmb[3], oy = tmb[7], oz = tmb[11];
        #pragma unroll
        for (int c = 0; c < 4; c++) {
            float s  = dx*wq[0*4+c] + dy*wq[1*4+c] + dz*wq[2*4+c];
            float bv = ox*wq[0*4+c] + oy*wq[1*4+c] + oz*wq[2*4+c]
                     + dx*wq[3*4+c] + dy*wq[4*4+c] + dz*wq[5*4+c];
            sA[q][c] = s * NL2E;
            bA[q][c] = bv * NL2E;
        }
    }

    // recurrence state: eV[c] = exp2(bA + d*sA) at the current coarse point,
    // kV[c] = per-step ratio exp2(sA*STEP). e00 = eV[0] at d = NEAR (kept for
    // phase 2 init).
    float eV[2][4], kV[2][4], e00[2];
    #pragma unroll
    for (int q = 0; q < 2; q++) {
        #pragma unroll
        for (int c = 0; c < 4; c++) {
            eV[q][c] = __builtin_amdgcn_exp2f(bA[q][c] + NEARV*sA[q][c]);
            kV[q][c] = __builtin_amdgcn_exp2f(sA[q][c]*STEPV);
        }
        e00[q] = eV[q][0];
    }

    // ---- phase 1: coarse march, 2 rays interleaved, zero exp2 ----
    float T[2] = {1.0f, 1.0f}, S[2] = {0.0f, 0.0f};
    float a0[2] = {0.0f, 0.0f}, a1[2] = {0.0f, 0.0f}, a2[2] = {0.0f, 0.0f};
    #pragma unroll 4
    for (int p = 0; p < PTS; p++) {
        #pragma unroll
        for (int q = 0; q < 2; q++) {
            float op = sig_e(eV[q][0]);
            float v0 = sig_e(eV[q][1]);
            float v1 = sig_e(eV[q][2]);
            float v2 = sig_e(eV[q][3]);
            eV[q][0] *= kV[q][0];
            eV[q][1] *= kV[q][1];
            eV[q][2] *= kV[q][2];
            eV[q][3] *= kV[q][3];
            float w  = op * T[q];
            a0[q] = fmaf(w, v0, a0[q]);
            a1[q] = fmaf(w, v1, a1[q]);
            a2[q] = fmaf(w, v2, a2[q]);
            S[q] += w + 1e-5f;
            T[q] *= (1.0f - op);
        }
    }
    #pragma unroll
    for (int q = 0; q < 2; q++) {
        out[(bb_[q]*3+0)*65536 + nn_[q]] = a0[q];
        out[(bb_[q]*3+1)*65536 + nn_[q]] = a1[q];
        out[(bb_[q]*3+2)*65536 + nn_[q]] = a2[q];
    }

    // ---- phase 2: branchless sampling machines, interleaved, zero exp2 ----
    // eP tracks exp2-value at coarse index m = min(ind+1, 63); advance (when
    // the min moves) is one conditional multiply by kV[0].
    float Sinv[2], T2[2], c_lo[2], c_hi[2], bin_prev[2], eP[2];
    int ind[2], kk[2];
    #pragma unroll
    for (int q = 0; q < 2; q++) {
        Sinv[q] = __builtin_amdgcn_rcpf(S[q]);
        float op0 = sig_e(e00[q]);           // sigmoid at d = NEAR (index 0)
        T2[q]   = 1.0f - op0;
        c_lo[q] = 0.0f;
        c_hi[q] = (op0 + 1e-5f) * Sinv[q];   // cdf[0]
        ind[q] = 0; kk[q] = 1;
        bin_prev[q] = NEARV;                 // bin_0 == NEAR always
        eP[q] = e00[q] * kV[q][0];           // index m = 1
    }
    #pragma unroll 2
    for (int it = 0; it < 2*PTS; it++) {
        #pragma unroll
        for (int q = 0; q < 2; q++) {
            float u = (float)kk[q] * 0.015625f;          // exact k/64
            bool adv = (ind[q] < PTS) && (c_hi[q] <= u); // searchsorted 'right'
            float opn = sig_e(eP[q]);                    // sigmoid at index m
            float wn  = opn * T2[q];
            float d0  = fmaf((float)(ind[q] - 1), STEPV, NEARV);
            float den = c_hi[q] - c_lo[q];
            den = (den < 1e-8f) ? 1.0f : den;            // ref guard
            float t = (u - c_lo[q]) * __builtin_amdgcn_rcpf(den);
            t = fminf(fmaxf(t, 0.0f), 1.0f);
            float bin = fmaf(t, STEPV, d0);
            bin = (ind[q] <= 0)   ? NEARV : bin;
            bin = (ind[q] >= PTS) ? FAR63 : bin;
            float fdep = 0.5f * (bin_prev[q] + bin);
            int widx = adv ? PTS : min(kk[q] - 1, PTS);  // pad row on advance
            fd[q][widx][tid] = fdep;                     // unconditional ds_write
            float nc_hi = c_hi[q] + (wn + 1e-5f) * Sinv[q];
            float nT2   = T2[q] * (1.0f - opn);
            // m = min(ind+1,63) increments iff adv && ind < 62
            float km    = (adv && (ind[q] < 62)) ? kV[q][0] : 1.0f;
            c_lo[q]     = adv ? c_hi[q] : c_lo[q];
            c_hi[q]     = adv ? nc_hi   : c_hi[q];
            T2[q]       = adv ? nT2     : T2[q];
            bin_prev[q] = adv ? bin_prev[q] : bin;
            eP[q]      *= km;
            ind[q] += adv ? 1 : 0;
            kk[q]  += adv ? 0 : 1;
        }
    }

    // ---- phase 3: branchless merge, 2 rays interleaved ----
    float T3[2] = {1.0f, 1.0f}, sw[2] = {0.0f, 0.0f};
    float f0[2] = {0.0f, 0.0f}, f1[2] = {0.0f, 0.0f}, f2[2] = {0.0f, 0.0f};
    float rd[2] = {0.0f, 0.0f};
    int pc[2] = {0, 0}, pf[2] = {0, 0};
    float dc[2] = {NEARV, NEARV};
    float cur[2], nxt[2];
    #pragma unroll
    for (int q = 0; q < 2; q++) { cur[q] = fd[q][0][tid]; nxt[q] = fd[q][1][tid]; }
    #pragma unroll 4
    for (int it = 0; it < 2*PTS; it++) {
        #pragma unroll
        for (int q = 0; q < 2; q++) {
            float dfv = (pf[q] < PTS) ? cur[q] : 3.0e38f;
            bool tc = (pc[q] < PTS) && (dc[q] <= dfv);   // ties -> coarse (stable)
            float d = tc ? dc[q] : dfv;
            pc[q] += tc ? 1 : 0;
            dc[q] = fmaf((float)pc[q], STEPV, NEARV);
            pf[q] += tc ? 0 : 1;
            cur[q] = tc ? cur[q] : nxt[q];
            nxt[q] = fd[q][min(pf[q] + 1, PTS)][tid];    // unconditional ds_read
            float op = sig_pm(bA[q][0] + d*sA[q][0]);
            float v0 = sig_pm(bA[q][1] + d*sA[q][1]);
            float v1 = sig_pm(bA[q][2] + d*sA[q][2]);
            float v2 = sig_pm(bA[q][3] + d*sA[q][3]);
            float w  = op * T3[q];
            f0[q] = fmaf(w, v0, f0[q]);
            f1[q] = fmaf(w, v1, f1[q]);
            f2[q] = fmaf(w, v2, f2[q]);
            sw[q] += w;
            rd[q] = fmaf(w, d, rd[q]);
            T3[q] *= (1.0f - op);
        }
    }

    unsigned kmn = 0xFFFFFFFFu, kmx = 0xFFFFFFFFu;
    #pragma unroll
    for (int q = 0; q < 2; q++) {
        out[393216 + (bb_[q]*3+0)*65536 + nn_[q]] = f0[q];
        out[393216 + (bb_[q]*3+1)*65536 + nn_[q]] = f1[q];
        out[393216 + (bb_[q]*3+2)*65536 + nn_[q]] = f2[q];
        float fop  = fminf(fmaxf(sw[q], 0.0f), 1.0f);
        float rdep = rd[q] + (1.0f - fop) * 2.0f;        // d_all.max() == 2.0 exactly
        out[786432 + rr[q]] = rdep;
        unsigned ub = __float_as_uint(rdep);             // rdep>0: u32 order == float order
        kmn = min(kmn, ub);
        kmx = min(kmx, ~ub);
    }
    #pragma unroll
    for (int m = 32; m >= 1; m >>= 1) {
        unsigned omn = (unsigned)__shfl_xor((int)kmn, m, 64);
        unsigned omx = (unsigned)__shfl_xor((int)kmx, m, 64);
        kmn = (omn < kmn) ? omn : kmn;
        kmx = (omx < kmx) ? omx : kmx;
    }
    if (tid == 0) {
        atomicMin(&mmx[0], kmn);
        atomicMin(&mmx[1], kmx);
    }
}

__global__ __launch_bounds__(256) void nerf_norm(float* __restrict__ out,
                                                 const unsigned int* __restrict__ mmx)
{
    int idx = blockIdx.x * 256 + threadIdx.x;
    float mn = __uint_as_float(mmx[0]);
    float mx = __uint_as_float(~mmx[1]);
    float v = out[786432 + idx];
    out[786432 + idx] = (v - mn) * __builtin_amdgcn_rcpf(mx - mn);
}

extern "C" void kernel_launch(void* const* d_in, const int* in_sizes, int n_in,
                              void* d_out, int out_size, void* d_ws, size_t ws_size,
                              hipStream_t stream) {
    (void)in_sizes; (void)n_in; (void)out_size; (void)ws_size;
    const float* tm = (const float*)d_in[0];
    const float* wq = (const float*)d_in[1];
    float* out = (float*)d_out;
    unsigned int* mmx = (unsigned int*)d_ws;
    hipMemsetAsync(d_ws, 0xFF, 8, stream);     // both min-keys -> UINT_MAX
    nerf_main<<<NRAYS/128, NT, 0, stream>>>(tm, wq, out, mmx);
    nerf_norm<<<NRAYS/256, 256, 0, stream>>>(out, mmx);
}